// Round 4
// baseline (31.461 us; speedup 1.0000x reference)
//
#include <hip/hip_runtime.h>
#include <hip/hip_fp16.h>
#include <cstdint>

#define IN_F 4096
#define OUT_F 11008
#define Q_OUT 5504
#define GROUP 128
#define BATCH 32

#define KBS 8          // k-splits (gridDim.y)
#define GPB 4          // quant groups per block (32/KBS)
#define NCH 8          // 64-k chunks per block
#define BN 64          // output cols per block
#define BROWS 66       // LDS ints per w-row: 64 data + 2 pad -> write bank=(8a8+2r+bk)%32 2-way (free)

typedef _Float16 f16x8 __attribute__((ext_vector_type(8)));
typedef float    f32x4 __attribute__((ext_vector_type(4)));

// ---------------------------------------------------------------------------
// Prepass: X f32 [32][4096] -> f16 in MFMA A-fragment order.
// slot(S,f,lane) = (S*2+f)*64 + lane holds (m = 16f + (lane&15),
// k = 32S + 8*(lane>>4) + j), j=0..7.
// ---------------------------------------------------------------------------
__global__ __launch_bounds__(256)
void xprep_kernel(const float* __restrict__ x, uint4* __restrict__ xf)
{
    const int t    = blockIdx.x * 256 + threadIdx.x;   // 0..16383
    const int lane = t & 63;
    const int f    = (t >> 6) & 1;
    const int S    = t >> 7;
    const int m    = f * 16 + (lane & 15);
    const int k0   = S * 32 + (lane >> 4) * 8;
    const float4* xr = reinterpret_cast<const float4*>(x + (size_t)m * IN_F + k0);
    float4 a = xr[0], b = xr[1];
    union { _Float16 h[8]; uint4 u; } v;
    v.h[0] = (_Float16)a.x; v.h[1] = (_Float16)a.y;
    v.h[2] = (_Float16)a.z; v.h[3] = (_Float16)a.w;
    v.h[4] = (_Float16)b.x; v.h[5] = (_Float16)b.y;
    v.h[6] = (_Float16)b.z; v.h[7] = (_Float16)b.w;
    xf[t] = v.u;
}

// ---------------------------------------------------------------------------
// Main GEMM: per block M=32, N=64, K=512. 4 waves, each owns 16 cols.
// A: 32 KB frag-ordered slice staged ONCE to LDS via global_load_lds (linear).
// B: raw int32 staged global->reg->LDS transposed [w][k] (stride 66), 2-deep
//    register prefetch; raw s_barrier + lgkmcnt(0) only (B loads stay in
//    flight across barriers). Dequant: f16 magic numbers fused into frags.
// ---------------------------------------------------------------------------
__global__ __launch_bounds__(256)
void int4_gemm_kernel(const uint4* __restrict__ xf,
                      const int*   __restrict__ qw,
                      const float* __restrict__ scales,
                      const int*   __restrict__ qz,
                      float*       __restrict__ partial)
{
    const int tid  = threadIdx.x;
    const int lane = tid & 63;
    const int wid  = tid >> 6;            // 0..3
    const int nb   = blockIdx.x;          // 0..171
    const int kb   = blockIdx.y;          // 0..7
    const int g0   = kb * GPB;
    const int k0b  = g0 * GROUP;          // block k base

    __shared__ uint4 a_lds[NCH * 4 * 64];     // 32 KB, single-buffered (read-only)
    __shared__ int   b_lds[2][32 * BROWS];    // 2 x 8.25 KB

    const int cl  = lane & 15;            // col within 16-col frag
    const int kg  = lane >> 4;            // k-group 0..3
    const int w   = wid * 8 + (cl >> 1);  // packed-word column 0..31
    const int shn = (cl & 1) * 4;         // nibble shift (even col -> low)

    // per-group dequant constants: packed f16 magic zero and scale
    const int n = nb * BN + wid * 16 + cl;
    uint    zmu[GPB];
    __half2 spk[GPB];
    #pragma unroll
    for (int g = 0; g < GPB; ++g) {
        const float s = scales[(size_t)(g0 + g) * OUT_F + n];
        const int   z = (qz[(size_t)(g0 + g) * Q_OUT + (n >> 1)] >> shn) & 15;
        spk[g] = __float2half2_rn(s);
        zmu[g] = 0x64006400u + (uint)z * 0x00010001u;   // packed f16 (1024+z, 1024+z)
    }

    // ---- A stage: this kb's 2048 contiguous uint4 slots -> LDS, linear ----
    {
        const size_t gbase = (size_t)(k0b / 32) * 2 * 64;   // first uint4 slot
        #pragma unroll
        for (int r = 0; r < 8; ++r) {
            const uint4* gp = xf + gbase + (size_t)r * 256 + tid;
            __builtin_amdgcn_global_load_lds(
                (const __attribute__((address_space(1))) uint32_t*)gp,
                (__attribute__((address_space(3))) uint32_t*)&a_lds[r * 256 + wid * 64],
                16, 0, 0);
        }
    }

    // B staging geometry: thread loads 2 x uint4 (rows bk, bk+32; words 4*a8..)
    const int a8 = tid & 7;
    const int bk = tid >> 3;              // 0..31

    f32x4 acc[2] = {};
    uint4 br0[2], br1[2];                 // 2-deep prefetch register sets

    auto LOADB = [&](int c, int set) {
        const int kr = k0b + c * 64;
        br0[set] = *reinterpret_cast<const uint4*>(qw + (size_t)(kr + bk)      * Q_OUT + nb * 32 + a8 * 4);
        br1[set] = *reinterpret_cast<const uint4*>(qw + (size_t)(kr + bk + 32) * Q_OUT + nb * 32 + a8 * 4);
    };
    auto WLDS = [&](int buf, int set) {
        int* p = b_lds[buf];
        p[(4 * a8 + 0) * BROWS + bk]      = br0[set].x;
        p[(4 * a8 + 1) * BROWS + bk]      = br0[set].y;
        p[(4 * a8 + 2) * BROWS + bk]      = br0[set].z;
        p[(4 * a8 + 3) * BROWS + bk]      = br0[set].w;
        p[(4 * a8 + 0) * BROWS + bk + 32] = br1[set].x;
        p[(4 * a8 + 1) * BROWS + bk + 32] = br1[set].y;
        p[(4 * a8 + 2) * BROWS + bk + 32] = br1[set].z;
        p[(4 * a8 + 3) * BROWS + bk + 32] = br1[set].w;
    };

    LOADB(0, 0);
    LOADB(1, 1);
    WLDS(0, 0);
    // prologue drain: A global_load_lds + B set0 ds_writes must be visible
    asm volatile("s_waitcnt vmcnt(0) lgkmcnt(0)" ::: "memory");
    __builtin_amdgcn_s_barrier();
    asm volatile("" ::: "memory");

    #pragma unroll
    for (int c = 0; c < NCH; ++c) {
        const int cur = c & 1;
        if (c + 2 < NCH) LOADB(c + 2, cur);   // refills set consumed at iter c-1

        const __half2 zmh = __builtin_bit_cast(__half2, zmu[c >> 1]);
        const __half2 sg  = spk[c >> 1];

        #pragma unroll
        for (int s = 0; s < 2; ++s) {
            const int* bp = &b_lds[cur][w * BROWS + s * 32 + kg * 8];
            int2 q0 = *reinterpret_cast<const int2*>(bp + 0);
            int2 q1 = *reinterpret_cast<const int2*>(bp + 2);
            int2 q2 = *reinterpret_cast<const int2*>(bp + 4);
            int2 q3 = *reinterpret_cast<const int2*>(bp + 6);

            union { uint u[4]; f16x8 v; } bf;
            const int2 qq[4] = {q0, q1, q2, q3};
            #pragma unroll
            for (int t = 0; t < 4; ++t) {
                uint pr = __builtin_amdgcn_perm((uint)qq[t].y, (uint)qq[t].x, 0x0C040C00u);
                pr >>= shn;
                uint qk = (pr & 0x000F000Fu) | 0x64006400u;
                __half2 wv = __hmul2(__hsub2(__builtin_bit_cast(__half2, qk), zmh), sg);
                bf.u[t] = __builtin_bit_cast(uint, wv);
            }
            uint4 a0u = a_lds[(c * 4 + s * 2 + 0) * 64 + lane];
            uint4 a1u = a_lds[(c * 4 + s * 2 + 1) * 64 + lane];
            f16x8 af0 = __builtin_bit_cast(f16x8, a0u);
            f16x8 af1 = __builtin_bit_cast(f16x8, a1u);
            acc[0] = __builtin_amdgcn_mfma_f32_16x16x32_f16(af0, bf.v, acc[0], 0, 0, 0);
            acc[1] = __builtin_amdgcn_mfma_f32_16x16x32_f16(af1, bf.v, acc[1], 0, 0, 0);
        }

        if (c + 1 < NCH) {
            WLDS(cur ^ 1, cur ^ 1);
            // only lgkmcnt: B prefetch loads legally stay in flight across barrier
            asm volatile("s_waitcnt lgkmcnt(0)" ::: "memory");
            __builtin_amdgcn_s_barrier();
            asm volatile("" ::: "memory");
        }
    }

    // epilogue: C/D layout col = lane&15, row = (lane>>4)*4 + reg  [m89]
    #pragma unroll
    for (int f = 0; f < 2; ++f) {
        const int m = f * 16 + kg * 4;
        float* pp = partial + ((size_t)(kb * BATCH + m)) * OUT_F + n;
        pp[0]                 = acc[f][0];
        pp[(size_t)OUT_F]     = acc[f][1];
        pp[(size_t)OUT_F * 2] = acc[f][2];
        pp[(size_t)OUT_F * 3] = acc[f][3];
    }
}

__global__ __launch_bounds__(256)
void reduce_bias_kernel(const float* __restrict__ partial,
                        const float* __restrict__ bias,
                        float* __restrict__ out)
{
    const int i4 = (blockIdx.x * 256 + threadIdx.x) * 4;   // < 352256
    const int n  = i4 % OUT_F;
    float4 s = *reinterpret_cast<const float4*>(bias + n);
    #pragma unroll
    for (int kb = 0; kb < KBS; ++kb) {
        float4 p = *reinterpret_cast<const float4*>(partial + (size_t)kb * BATCH * OUT_F + i4);
        s.x += p.x; s.y += p.y; s.z += p.z; s.w += p.w;
    }
    *reinterpret_cast<float4*>(out + i4) = s;
}

extern "C" void kernel_launch(void* const* d_in, const int* in_sizes, int n_in,
                              void* d_out, int out_size, void* d_ws, size_t ws_size,
                              hipStream_t stream)
{
    const float* inp    = (const float*)d_in[0];
    const int*   qw     = (const int*)d_in[1];
    const float* scales = (const float*)d_in[2];
    const int*   qz     = (const int*)d_in[3];
    const float* bias   = (const float*)d_in[4];
    float*       out    = (float*)d_out;

    const size_t XFB = (size_t)BATCH * IN_F * 2;            // 256 KB f16 X (frag order)
    uint4* xf      = (uint4*)d_ws;
    float* partial = (float*)((char*)d_ws + XFB);           // KBS * 1.41 MB

    xprep_kernel<<<64, 256, 0, stream>>>(inp, xf);

    int4_gemm_kernel<<<dim3(OUT_F / BN, KBS), 256, 0, stream>>>(
        xf, qw, scales, qz, partial);

    reduce_bias_kernel<<<(BATCH * OUT_F) / 1024, 256, 0, stream>>>(partial, bias, out);
}

// Round 5
// 28.407 us; speedup vs baseline: 1.1075x; 1.1075x over previous
//
#include <hip/hip_runtime.h>
#include <cstdint>

#define IN_F 4096
#define OUT_F 11008
#define Q_OUT 5504
#define GROUP 128
#define BATCH 32

#define KBS 8            // k-splits (gridDim.y)
#define GPB 4            // quant groups per block
#define NCH 8            // 64-k chunks per block
#define BN 64            // output cols per block
#define BST 18           // b_lds dword stride per n-row: 16 data + 2 pad
                         // -> read banks uniform (conflict-free b64), writes ~4-way

typedef int   i32x4 __attribute__((ext_vector_type(4)));
typedef float f32x4 __attribute__((ext_vector_type(4)));

// ---------------------------------------------------------------------------
// Prep kernel, two roles by blockIdx:
//  blocks 0..31: row m: maxabs -> delta[m]; quantize x to i8 in MFMA A-frag
//    order (16x16x64: lane l holds m=16f+(l&15), k=16*(l>>4)+j); per-group
//    row sums Sx[g][m] (i32, exact).
//  blocks 32..375: out[m][n] = bias[n]  (fresh every launch; gemm atomics add)
// ---------------------------------------------------------------------------
__global__ __launch_bounds__(256)
void prep_kernel(const float* __restrict__ x,
                 const float* __restrict__ bias,
                 uint4* __restrict__ xq,     // 8192 slots of 16 i8
                 int*   __restrict__ Sx,     // [32 g][32 m]
                 float* __restrict__ delta,  // [32]
                 float* __restrict__ out)
{
    const int t = threadIdx.x;
    if (blockIdx.x >= 32) {
        const int j4 = ((blockIdx.x - 32) * 256 + t) * 4;
        *reinterpret_cast<float4*>(out + j4) =
            *reinterpret_cast<const float4*>(bias + (j4 % OUT_F));
        return;
    }
    const int m = blockIdx.x;
    const float* xr = x + (size_t)m * IN_F + t * 16;  // thread owns k=16t..16t+15
    float4 v[4];
    #pragma unroll
    for (int i = 0; i < 4; ++i) v[i] = reinterpret_cast<const float4*>(xr)[i];

    float lm = 0.f;
    #pragma unroll
    for (int i = 0; i < 4; ++i) {
        lm = fmaxf(lm, fmaxf(fmaxf(fabsf(v[i].x), fabsf(v[i].y)),
                             fmaxf(fabsf(v[i].z), fabsf(v[i].w))));
    }
    #pragma unroll
    for (int d = 32; d; d >>= 1) lm = fmaxf(lm, __shfl_xor(lm, d));
    __shared__ float wred[4];
    if ((t & 63) == 0) wred[t >> 6] = lm;
    __syncthreads();
    const float mx  = fmaxf(fmaxf(wred[0], wred[1]), fmaxf(wred[2], wred[3]));
    const float inv = mx > 0.f ? 127.0f / mx : 0.f;

    int q[16];
    #pragma unroll
    for (int i = 0; i < 4; ++i) {
        q[i * 4 + 0] = __float2int_rn(v[i].x * inv);
        q[i * 4 + 1] = __float2int_rn(v[i].y * inv);
        q[i * 4 + 2] = __float2int_rn(v[i].z * inv);
        q[i * 4 + 3] = __float2int_rn(v[i].w * inv);
    }
    uint4 w;
    uint* wp = reinterpret_cast<uint*>(&w);
    #pragma unroll
    for (int i = 0; i < 4; ++i)
        wp[i] = (q[i*4] & 255) | ((q[i*4+1] & 255) << 8) |
                ((q[i*4+2] & 255) << 16) | ((q[i*4+3] & 255) << 24);
    // slot = (S*2 + f)*64 + kg*16 + (m&15);  S=t>>2, kg=t&3, f=m>>4
    xq[(t >> 2) * 128 + (m >> 4) * 64 + (t & 3) * 16 + (m & 15)] = w;

    int psum = 0;
    #pragma unroll
    for (int i = 0; i < 16; ++i) psum += q[i];
    #pragma unroll
    for (int d = 4; d; d >>= 1) psum += __shfl_down(psum, d, 8);
    if ((t & 7) == 0) Sx[(t >> 3) * 32 + m] = psum;   // g = t>>3
    if (t == 0) delta[m] = mx * (1.0f / 127.0f);
}

// ---------------------------------------------------------------------------
// GEMM: per block M=32, N=64, K=512 (4 groups). 4 waves, each 16 cols.
// A: i8 frags, 16 KB staged once via global_load_lds; 2 x ds_read_b128/chunk.
// B: nibbles unpacked to i8 bytes in LDS [n][k] (stride 18 dwords), 4 packed
//    k per dword; 2-deep register prefetch; raw barrier + lgkmcnt only.
// Per group: acc_i32 -> accf += s*(D - z*Sx); epilogue: out += delta_m * accf
// via unsafeAtomicAdd (out pre-initialized with bias by prep).
// ---------------------------------------------------------------------------
__global__ __launch_bounds__(256, 4)
void int4_gemm_i8(const uint4* __restrict__ xq,
                  const int*   __restrict__ qw,
                  const float* __restrict__ scales,
                  const int*   __restrict__ qz,
                  const int*   __restrict__ Sx,
                  const float* __restrict__ delta,
                  float*       __restrict__ out)
{
    const int tid  = threadIdx.x;
    const int lane = tid & 63;
    const int wid  = tid >> 6;
    const int nb   = blockIdx.x;          // 0..171
    const int kb   = blockIdx.y;          // 0..7
    const int g0   = kb * GPB;
    const int k0b  = g0 * GROUP;

    __shared__ uint4 a_lds[1024];         // 16 KB, read-only after prologue
    __shared__ int   b_lds[2][64 * BST];  // 2 x 4.5 KB

    const int cl  = lane & 15;
    const int kg  = lane >> 4;
    const int n   = nb * BN + wid * 16 + cl;
    const int shn = (cl & 1) * 4;

    // ---- A stage: this kb's 1024 contiguous uint4 slots -> LDS, linear ----
    #pragma unroll
    for (int r = 0; r < 4; ++r) {
        const uint4* gp = xq + (size_t)kb * 1024 + r * 256 + tid;
        __builtin_amdgcn_global_load_lds(
            (const __attribute__((address_space(1))) uint32_t*)gp,
            (__attribute__((address_space(3))) uint32_t*)&a_lds[r * 256 + wid * 64],
            16, 0, 0);
    }

    // per-group constants
    int   zv[GPB];
    float sv[GPB];
    #pragma unroll
    for (int g = 0; g < GPB; ++g) {
        sv[g] = scales[(size_t)(g0 + g) * OUT_F + n];
        zv[g] = (qz[(size_t)(g0 + g) * Q_OUT + (n >> 1)] >> shn) & 15;
    }

    // B staging: thread (a16 = words 2a16,2a16+1; rk = rows 4rk..4rk+3)
    const int a16 = tid & 15;
    const int rk  = tid >> 4;

    uint2 d[2][4];                        // [set][row], fully unrolled indexing
    i32x4 acc_i[2] = {};
    f32x4 accf[2]  = {};
    int4  sx0v = {}, sx1v = {};

    auto LOADB = [&](int c, int set) {
        const int kr = k0b + c * 64 + 4 * rk;
        #pragma unroll
        for (int i = 0; i < 4; ++i)
            d[set][i] = *reinterpret_cast<const uint2*>(
                qw + (size_t)(kr + i) * Q_OUT + nb * 32 + 2 * a16);
    };
    auto WLDS = [&](int buf, int set) {
        #pragma unroll
        for (int j = 0; j < 2; ++j) {
            uint b0 = (j ? d[set][0].y : d[set][0].x) & 255u;
            uint b1 = (j ? d[set][1].y : d[set][1].x) & 255u;
            uint b2 = (j ? d[set][2].y : d[set][2].x) & 255u;
            uint b3 = (j ? d[set][3].y : d[set][3].x) & 255u;
            uint p  = b0 | (b1 << 8) | (b2 << 16) | (b3 << 24);
            const int nloc = 4 * a16 + 2 * j;
            b_lds[buf][(nloc + 0) * BST + rk] = (int)(p & 0x0F0F0F0Fu);
            b_lds[buf][(nloc + 1) * BST + rk] = (int)((p >> 4) & 0x0F0F0F0Fu);
        }
    };

    LOADB(0, 0);
    LOADB(1, 1);
    WLDS(0, 0);
    asm volatile("s_waitcnt vmcnt(0) lgkmcnt(0)" ::: "memory");
    __builtin_amdgcn_s_barrier();
    asm volatile("" ::: "memory");

    #pragma unroll
    for (int c = 0; c < NCH; ++c) {
        const int cur = c & 1;
        const int gl  = c >> 1;
        if (c + 2 < NCH) LOADB(c + 2, cur);
        if ((c & 1) == 0) {   // group start: fetch Sx rows (L2-hot, used next chunk)
            sx0v = *reinterpret_cast<const int4*>(Sx + (g0 + gl) * 32 + kg * 4);
            sx1v = *reinterpret_cast<const int4*>(Sx + (g0 + gl) * 32 + 16 + kg * 4);
        }

        // B fragment: n-row, dwords 4kg..4kg+3 (16 consecutive k bytes)
        const int* bp = &b_lds[cur][(wid * 16 + cl) * BST + 4 * kg];
        int2 qa = *reinterpret_cast<const int2*>(bp);
        int2 qb = *reinterpret_cast<const int2*>(bp + 2);
        i32x4 bv; bv[0] = qa.x; bv[1] = qa.y; bv[2] = qb.x; bv[3] = qb.y;

        uint4 a0 = a_lds[(c * 2 + 0) * 64 + lane];
        uint4 a1 = a_lds[(c * 2 + 1) * 64 + lane];
        acc_i[0] = __builtin_amdgcn_mfma_i32_16x16x64_i8(
            __builtin_bit_cast(i32x4, a0), bv, acc_i[0], 0, 0, 0);
        acc_i[1] = __builtin_amdgcn_mfma_i32_16x16x64_i8(
            __builtin_bit_cast(i32x4, a1), bv, acc_i[1], 0, 0, 0);

        if (c & 1) {          // group end: integer zero-point fixup, scale to f32
            const int   zz = zv[gl];
            const float ss = sv[gl];
            int sxa[8] = { sx0v.x, sx0v.y, sx0v.z, sx0v.w,
                           sx1v.x, sx1v.y, sx1v.z, sx1v.w };
            #pragma unroll
            for (int f = 0; f < 2; ++f)
                #pragma unroll
                for (int r = 0; r < 4; ++r) {
                    int tt = acc_i[f][r] - zz * sxa[f * 4 + r];
                    accf[f][r] = fmaf(ss, (float)tt, accf[f][r]);
                }
            acc_i[0] = i32x4{0, 0, 0, 0};
            acc_i[1] = i32x4{0, 0, 0, 0};
        }

        if (c + 1 < NCH) {
            WLDS(cur ^ 1, cur ^ 1);
            asm volatile("s_waitcnt lgkmcnt(0)" ::: "memory");
            __builtin_amdgcn_s_barrier();
            asm volatile("" ::: "memory");
        }
    }

    // epilogue: C/D layout col=lane&15, row=(lane>>4)*4+reg; out += delta_m*accf
    float4 dl0 = *reinterpret_cast<const float4*>(delta + kg * 4);
    float4 dl1 = *reinterpret_cast<const float4*>(delta + 16 + kg * 4);
    const float dla[8] = { dl0.x, dl0.y, dl0.z, dl0.w, dl1.x, dl1.y, dl1.z, dl1.w };
    #pragma unroll
    for (int f = 0; f < 2; ++f)
        #pragma unroll
        for (int r = 0; r < 4; ++r) {
            const int m = f * 16 + kg * 4 + r;
            unsafeAtomicAdd(out + (size_t)m * OUT_F + n, dla[f * 4 + r] * accf[f][r]);
        }
}

extern "C" void kernel_launch(void* const* d_in, const int* in_sizes, int n_in,
                              void* d_out, int out_size, void* d_ws, size_t ws_size,
                              hipStream_t stream)
{
    const float* inp    = (const float*)d_in[0];
    const int*   qw     = (const int*)d_in[1];
    const float* scales = (const float*)d_in[2];
    const int*   qz     = (const int*)d_in[3];
    const float* bias   = (const float*)d_in[4];
    float*       out    = (float*)d_out;

    uint4* xq    = (uint4*)d_ws;                         // 128 KB
    int*   Sx    = (int*)((char*)d_ws + 131072);         // 4 KB
    float* delta = (float*)((char*)d_ws + 131072 + 4096);// 128 B

    // blocks 0..31: quantize rows + Sx + delta; blocks 32..375: out = bias
    prep_kernel<<<376, 256, 0, stream>>>(inp, bias, xq, Sx, delta, out);

    int4_gemm_i8<<<dim3(OUT_F / BN, KBS), 256, 0, stream>>>(
        xq, qw, scales, qz, Sx, delta, out);
}